// Round 18
// baseline (201.572 us; speedup 1.0000x reference)
//
#include <hip/hip_runtime.h>
#include <hip/hip_bf16.h>
#include <math.h>

#define Hd 128
#define Tt 256
#define Bb 1024
#define CL 32           // time-chunk length
#define NCK (Tt / CL)   // 8 chunks

typedef __attribute__((ext_vector_type(8))) short short8;
typedef __attribute__((ext_vector_type(4))) float f32x4;

__device__ __forceinline__ short f2bf(float f) {
    unsigned u = __float_as_uint(f);
    u += 0x7fffu + ((u >> 16) & 1u);   // RNE
    return (short)(u >> 16);
}
__device__ __forceinline__ float bflo(unsigned u) { return __uint_as_float(u << 16); }
__device__ __forceinline__ float bfhi(unsigned u) { return __uint_as_float(u & 0xffff0000u); }

// Weights -> bf16 MFMA B-frag layout [nt][kf][lane][8].  (verbatim)
__global__ void prep_weights(const float* __restrict__ Wih,
                             const float* __restrict__ Whh,
                             const float* __restrict__ fcW,
                             short* __restrict__ oIh, short* __restrict__ oHh,
                             short* __restrict__ oFc) {
    int t = blockIdx.x * 256 + threadIdx.x;
    if (t >= 14336) return;
    const float* src;
    short* dst;
    if (t < 6144)       { src = Wih; dst = oIh + t * 8; }
    else if (t < 12288) { t -= 6144;  src = Whh; dst = oHh + t * 8; }
    else                { t -= 12288; src = fcW; dst = oFc + t * 8; }
    int lane = t & 63, kf = (t >> 6) & 3, nt = t >> 8;
    const float* s = src + (nt * 16 + (lane & 15)) * 128 + kf * 32 + 8 * (lane >> 4);
#pragma unroll
    for (int j = 0; j < 8; j++) dst[j] = f2bf(s[j]);
}

// K2: xi = x@W_ih^T (+bih, +bhh for r/z cols) in C-frag order (R14: 8 frames
// per block). R18: x loads are NON-TEMPORAL (read-once 134 MB must not evict
// the 201 MB xi buffer we are trying to keep L3-resident for gru_chunk).
__global__ __launch_bounds__(512)
void xi_gemm(const float* __restrict__ x, const float* __restrict__ bih,
             const float* __restrict__ bhh, const short* __restrict__ wIh,
             short* __restrict__ xi_l) {
    __shared__ short xs[128 * 136];
    const int tid = threadIdx.x, wv = tid >> 6, ln = tid & 63;
    const int q = ln & 15, lg = ln >> 4;
    const int bg = blockIdx.x;
    const int sl0 = blockIdx.y * 8;
    {
        const int row = tid >> 2, kq = tid & 3;
        const int b = row & 15, dt = row >> 4;
        const float* xp = x + (((size_t)(bg * 16 + b)) * Tt + (sl0 + dt)) * Hd + kq * 32;
        short* dp = &xs[row * 136 + kq * 32];
#pragma unroll
        for (int h = 0; h < 2; h++) {
            f32x4 u0 = __builtin_nontemporal_load((const f32x4*)&xp[16 * h]);
            f32x4 u1 = __builtin_nontemporal_load((const f32x4*)&xp[16 * h + 4]);
            f32x4 u2 = __builtin_nontemporal_load((const f32x4*)&xp[16 * h + 8]);
            f32x4 u3 = __builtin_nontemporal_load((const f32x4*)&xp[16 * h + 12]);
            short8 s0, s1;
#pragma unroll
            for (int i = 0; i < 4; i++) { s0[i] = f2bf(u0[i]); s0[i+4] = f2bf(u1[i]);
                                          s1[i] = f2bf(u2[i]); s1[i+4] = f2bf(u3[i]); }
            *(short8*)(dp + 16 * h) = s0;
            *(short8*)(dp + 16 * h + 8) = s1;
        }
    }
    __syncthreads();
    short8 wb[3][4];
#pragma unroll
    for (int i = 0; i < 3; i++)
#pragma unroll
        for (int kf = 0; kf < 4; kf++)
            wb[i][kf] = *(const short8*)&wIh[(((wv + 8 * i) * 4 + kf) * 64 + ln) * 8];
    float biasv[3];
#pragma unroll
    for (int i = 0; i < 3; i++) {
        int c = (wv + 8 * i) * 16 + q;
        biasv[i] = bih[c] + (c < 256 ? bhh[c] : 0.f);
    }
#pragma unroll 2
    for (int mt = 0; mt < 8; mt++) {
        short8 af[4];
#pragma unroll
        for (int kf = 0; kf < 4; kf++)
            af[kf] = *(const short8*)&xs[(mt * 16 + q) * 136 + kf * 32 + 8 * lg];
        f32x4 c0 = {0,0,0,0}, c1 = {0,0,0,0}, c2 = {0,0,0,0};
#pragma unroll
        for (int kf = 0; kf < 4; kf++) {
            c0 = __builtin_amdgcn_mfma_f32_16x16x32_bf16(af[kf], wb[0][kf], c0, 0, 0, 0);
            c1 = __builtin_amdgcn_mfma_f32_16x16x32_bf16(af[kf], wb[1][kf], c1, 0, 0, 0);
            c2 = __builtin_amdgcn_mfma_f32_16x16x32_bf16(af[kf], wb[2][kf], c2, 0, 0, 0);
        }
#pragma unroll
        for (int i = 0; i < 3; i++) {
            f32x4 cc = (i == 0) ? c0 : (i == 1) ? c1 : c2;
            unsigned d0 = (unsigned)(unsigned short)f2bf(cc[0] + biasv[i]) |
                          ((unsigned)(unsigned short)f2bf(cc[1] + biasv[i]) << 16);
            unsigned d1 = (unsigned)(unsigned short)f2bf(cc[2] + biasv[i]) |
                          ((unsigned)(unsigned short)f2bf(cc[3] + biasv[i]) << 16);
            uint2 dd = {d0, d1};
            ((uint2*)xi_l)[(((size_t)bg * Tt + (sl0 + mt)) * 24 + (wv + 8 * i)) * 64 + ln] = dd;
        }
    }
}

// K3: R12 gru_chunk + R18 deltas: (1) NON-TEMPORAL out stores -- the 131 MB
// out stream was evicting the 201 MB (< 256 MB L3) xi buffer, forcing gru to
// re-FETCH 111 MB of xi from HBM at ~900cy instead of L3 ~200cy;
// (2) cvt_pk h-writeback (proven in R14's passing gru; -12 VALU/step).
__global__ __launch_bounds__(256)
void gru_chunk(const short* __restrict__ xi_l, const int* __restrict__ done,
               const float* __restrict__ h0,
               const float* __restrict__ bhh, const float* __restrict__ fcb,
               const short* __restrict__ wHh, const short* __restrict__ wFc,
               float* __restrict__ out, float* __restrict__ hlast) {
    __shared__ short hT[2][16 * 136];
    __shared__ int doneL[Tt * 16];
    __shared__ int rbL[16];
    const int tid = threadIdx.x, j = tid >> 6, ln = tid & 63;
    const int q = ln & 15, lg = ln >> 4;
    const int bg = blockIdx.x, ck = blockIdx.y;
    const int t_c = ck * CL, t_end = t_c + CL;

    {   // stage done[b][0..t_end) -> doneL[t][b]
        const int b = tid >> 4, i = tid & 15;
        const int* dp = done + (size_t)(bg * 16 + b) * Tt;
        for (int t = i; t < t_end; t += 16) doneL[t * 16 + b] = dp[t];
    }
    __syncthreads();
    if (tid < 16) {   // last reset before t_c
        int r = 0;
        for (int t = t_c - 1; t >= 0; --t)
            if (doneL[t * 16 + tid]) { r = t + 1; break; }
        rbL[tid] = r;
    }
    __syncthreads();
    int rmin = rbL[0];
#pragma unroll
    for (int b = 1; b < 16; b++) rmin = min(rmin, rbL[b]);

    short8 whh[6][4], wfc[2][4];
#pragma unroll
    for (int i = 0; i < 6; i++)
#pragma unroll
        for (int kf = 0; kf < 4; kf++)
            whh[i][kf] = *(const short8*)&wHh[(((j + 4 * i) * 4 + kf) * 64 + ln) * 8];
#pragma unroll
    for (int cs = 0; cs < 2; cs++)
#pragma unroll
        for (int kf = 0; kf < 4; kf++)
            wfc[cs][kf] = *(const short8*)&wFc[(((j + 4 * cs) * 4 + kf) * 64 + ln) * 8];
    float cbn[2], cbf[2];
#pragma unroll
    for (int cs = 0; cs < 2; cs++) {
        int c = 16 * j + 64 * cs + q;
        cbn[cs] = bhh[256 + c];
        cbf[cs] = fcb[c];
    }

    float h_reg[2][4];
#pragma unroll
    for (int cs = 0; cs < 2; cs++)
#pragma unroll
        for (int r = 0; r < 4; r++) {
            int bb = 4 * lg + r, c = 16 * j + 64 * cs + q;
            h_reg[cs][r] = (rbL[bb] == 0) ? h0[(size_t)(bg * 16 + bb) * Hd + c] : 0.f;
        }
    {   // hT[rmin&1] <- h_init (h0 if r_b==0 else 0)
        int row = tid >> 4, c0 = (tid & 15) * 8;
        short8 s0 = {0,0,0,0,0,0,0,0};
        if (rbL[row] == 0) {
            const float* hp = &h0[(size_t)(bg * 16 + row) * Hd + c0];
            f32x4 u0 = *(const f32x4*)&hp[0], u1 = *(const f32x4*)&hp[4];
#pragma unroll
            for (int i = 0; i < 4; i++) { s0[i] = f2bf(u0[i]); s0[i+4] = f2bf(u1[i]); }
        }
        *(short8*)&hT[rmin & 1][row * 136 + c0] = s0;
    }
    __syncthreads();

    // xi pointer: tile (j+4i) at xp + i*256 (uint2), one t = +1536
    const uint2* xp = (const uint2*)xi_l + ((size_t)bg * Tt + rmin) * 1536 + j * 64 + ln;
    uint2 cur[6];
#pragma unroll
    for (int i = 0; i < 6; i++) cur[i] = xp[i * 256];
    xp += 1536;

#pragma unroll 1
    for (int t = rmin; t < t_end; ++t) {
        const short* hTp = &hT[t & 1][0];
        short* hTn = &hT[(t + 1) & 1][0];
        short8 haf[4];
#pragma unroll
        for (int kf = 0; kf < 4; kf++)
            haf[kf] = *(const short8*)&hTp[q * 136 + kf * 32 + 8 * lg];

        // consume cur(t) -> acc init + xn8, then ISSUE loads for t+1 (older
        // than this iter's stores in vmcnt order)
        f32x4 acc[6];
#pragma unroll
        for (int i = 0; i < 4; i++) {
            f32x4 a = {bflo(cur[i].x), bfhi(cur[i].x), bflo(cur[i].y), bfhi(cur[i].y)};
            acc[i] = a;
        }
        { f32x4 a = {cbn[0], cbn[0], cbn[0], cbn[0]}; acc[4] = a; }
        { f32x4 a = {cbn[1], cbn[1], cbn[1], cbn[1]}; acc[5] = a; }
        uint2 xn8[2] = {cur[4], cur[5]};
        if (t + 1 < t_end) {
#pragma unroll
            for (int i = 0; i < 6; i++) cur[i] = xp[i * 256];
        }
        xp += 1536;

        if (t > t_c) {   // FC+ELU+stores for frame t-1 (un-reset haf)
            f32x4 fca[2];
            { f32x4 a = {cbf[0], cbf[0], cbf[0], cbf[0]}; fca[0] = a; }
            { f32x4 a = {cbf[1], cbf[1], cbf[1], cbf[1]}; fca[1] = a; }
#pragma unroll
            for (int kf = 0; kf < 4; kf++)
#pragma unroll
                for (int cs = 0; cs < 2; cs++)
                    fca[cs] = __builtin_amdgcn_mfma_f32_16x16x32_bf16(haf[kf], wfc[cs][kf], fca[cs], 0, 0, 0);
#pragma unroll
            for (int cs = 0; cs < 2; cs++)
#pragma unroll
                for (int r = 0; r < 4; r++) {
                    int bb = 4 * lg + r, c = 16 * j + 64 * cs + q;
                    float v = fca[cs][r];
                    float e = __expf(v) - 1.f;
                    v = v > 0.f ? v : e;
                    __builtin_nontemporal_store(
                        v, &out[(((size_t)(bg * 16 + bb)) * Tt + (t - 1)) * Hd + c]);
                }
        }

        if (t > 0) {   // reset haf in place (FC above used un-reset value)
            int dn = doneL[(t - 1) * 16 + q];
            short8 z8 = {0,0,0,0,0,0,0,0};
#pragma unroll
            for (int kf = 0; kf < 4; kf++) haf[kf] = dn ? z8 : haf[kf];
        }
        __builtin_amdgcn_s_setprio(1);   // favor the h-critical region
#pragma unroll
        for (int kf = 0; kf < 4; kf++)
#pragma unroll
            for (int i = 0; i < 6; i++)
                acc[i] = __builtin_amdgcn_mfma_f32_16x16x32_bf16(haf[kf], whh[i][kf], acc[i], 0, 0, 0);

        float rstf[4] = {1.f, 1.f, 1.f, 1.f};
        if (t > 0) {
            int4 dd = *(const int4*)&doneL[(t - 1) * 16 + 4 * lg];
            rstf[0] = dd.x ? 0.f : 1.f; rstf[1] = dd.y ? 0.f : 1.f;
            rstf[2] = dd.z ? 0.f : 1.f; rstf[3] = dd.w ? 0.f : 1.f;
        }
#pragma unroll
        for (int cs = 0; cs < 2; cs++) {
            float hn_[4];
#pragma unroll
            for (int r = 0; r < 4; r++) {
                float rg = __builtin_amdgcn_rcpf(1.f + __expf(-acc[cs][r]));
                float zg = __builtin_amdgcn_rcpf(1.f + __expf(-acc[2 + cs][r]));
                float xn = (r == 0) ? bflo(xn8[cs].x) : (r == 1) ? bfhi(xn8[cs].x)
                         : (r == 2) ? bflo(xn8[cs].y) : bfhi(xn8[cs].y);
                float aa = fmaf(rg, acc[4 + cs][r], xn);
                float ng = 1.f - 2.f * __builtin_amdgcn_rcpf(__expf(2.f * aa) + 1.f);
                float hp = h_reg[cs][r] * rstf[r];
                float hn = (1.f - zg) * ng + zg * hp;
                h_reg[cs][r] = hn;                       // un-reset
                hn_[r] = hn;
            }
            unsigned pk0, pk1;
            asm("v_cvt_pk_bf16_f32 %0, %1, %2" : "=v"(pk0) : "v"(hn_[0]), "v"(hn_[1]));
            asm("v_cvt_pk_bf16_f32 %0, %1, %2" : "=v"(pk1) : "v"(hn_[2]), "v"(hn_[3]));
            hTn[(4 * lg + 0) * 136 + 16 * j + 64 * cs + q] = (short)pk0;
            hTn[(4 * lg + 1) * 136 + 16 * j + 64 * cs + q] = (short)(pk0 >> 16);
            hTn[(4 * lg + 2) * 136 + 16 * j + 64 * cs + q] = (short)pk1;
            hTn[(4 * lg + 3) * 136 + 16 * j + 64 * cs + q] = (short)(pk1 >> 16);
        }
        __builtin_amdgcn_s_setprio(0);
        // raw barrier: lgkmcnt(0) only, semantic intrinsic
        __builtin_amdgcn_sched_barrier(0);
        __builtin_amdgcn_s_waitcnt(0xC07F);
        __builtin_amdgcn_s_barrier();
        __builtin_amdgcn_sched_barrier(0);
    }
    {   // epilogue FC for frame t_end-1 (slot t_end&1 holds h_{t_end-1})
        const short* hTp = &hT[t_end & 1][0];
        short8 haf[4];
#pragma unroll
        for (int kf = 0; kf < 4; kf++)
            haf[kf] = *(const short8*)&hTp[q * 136 + kf * 32 + 8 * lg];
        f32x4 fca[2];
        { f32x4 a = {cbf[0], cbf[0], cbf[0], cbf[0]}; fca[0] = a; }
        { f32x4 a = {cbf[1], cbf[1], cbf[1], cbf[1]}; fca[1] = a; }
#pragma unroll
        for (int kf = 0; kf < 4; kf++)
#pragma unroll
            for (int cs = 0; cs < 2; cs++)
                fca[cs] = __builtin_amdgcn_mfma_f32_16x16x32_bf16(haf[kf], wfc[cs][kf], fca[cs], 0, 0, 0);
#pragma unroll
        for (int cs = 0; cs < 2; cs++)
#pragma unroll
            for (int r = 0; r < 4; r++) {
                int bb = 4 * lg + r, c = 16 * j + 64 * cs + q;
                float v = fca[cs][r];
                float e = __expf(v) - 1.f;
                v = v > 0.f ? v : e;
                __builtin_nontemporal_store(
                    v, &out[(((size_t)(bg * 16 + bb)) * Tt + (t_end - 1)) * Hd + c]);
            }
    }
    if (ck == NCK - 1) {   // h after step 255, un-reset
#pragma unroll
        for (int cs = 0; cs < 2; cs++)
#pragma unroll
            for (int r = 0; r < 4; r++) {
                int bb = 4 * lg + r, c = 16 * j + 64 * cs + q;
                hlast[(size_t)(bg * 16 + bb) * Hd + c] = h_reg[cs][r];
            }
    }
}

extern "C" void kernel_launch(void* const* d_in, const int* in_sizes, int n_in,
                              void* d_out, int out_size, void* d_ws, size_t ws_size,
                              hipStream_t stream) {
    const float* x   = (const float*)d_in[0];
    const float* h0  = (const float*)d_in[1];
    const int*   dn  = (const int*)d_in[2];
    const float* Wih = (const float*)d_in[3];
    const float* Whh = (const float*)d_in[4];
    const float* bih = (const float*)d_in[5];
    const float* bhh = (const float*)d_in[6];
    const float* fcW = (const float*)d_in[7];
    const float* fcb = (const float*)d_in[8];

    short* wIh = (short*)d_ws;                 // 96 KB
    short* wHh = wIh + 49152;                  // 96 KB
    short* wFc = wHh + 49152;                  // 32 KB
    short* xi_l = wFc + 16384;                 // full-T xi: 201 MB (L3-resident)
    float* out = (float*)d_out;
    float* hlast = out + (size_t)Bb * Tt * Hd;

    prep_weights<<<56, 256, 0, stream>>>(Wih, Whh, fcW, wIh, wHh, wFc);
    xi_gemm<<<dim3(64, Tt / 8), 512, 0, stream>>>(x, bih, bhh, wIh, xi_l);
    gru_chunk<<<dim3(64, NCK), 256, 0, stream>>>(xi_l, dn, h0, bhh, fcb,
                                                 wHh, wFc, out, hlast);
}

// Round 19
// 166.746 us; speedup vs baseline: 1.2089x; 1.2089x over previous
//
#include <hip/hip_runtime.h>
#include <hip/hip_bf16.h>
#include <math.h>

#define Hd 128
#define Tt 256
#define Bb 1024
#define CL 32           // time-chunk length
#define NCK (Tt / CL)   // 8 chunks

typedef __attribute__((ext_vector_type(8))) short short8;
typedef __attribute__((ext_vector_type(4))) float f32x4;

__device__ __forceinline__ short f2bf(float f) {
    unsigned u = __float_as_uint(f);
    u += 0x7fffu + ((u >> 16) & 1u);   // RNE
    return (short)(u >> 16);
}
__device__ __forceinline__ float bflo(unsigned u) { return __uint_as_float(u << 16); }
__device__ __forceinline__ float bfhi(unsigned u) { return __uint_as_float(u & 0xffff0000u); }

// Weights -> bf16 MFMA B-frag layout [nt][kf][lane][8].  (verbatim)
__global__ void prep_weights(const float* __restrict__ Wih,
                             const float* __restrict__ Whh,
                             const float* __restrict__ fcW,
                             short* __restrict__ oIh, short* __restrict__ oHh,
                             short* __restrict__ oFc) {
    int t = blockIdx.x * 256 + threadIdx.x;
    if (t >= 14336) return;
    const float* src;
    short* dst;
    if (t < 6144)       { src = Wih; dst = oIh + t * 8; }
    else if (t < 12288) { t -= 6144;  src = Whh; dst = oHh + t * 8; }
    else                { t -= 12288; src = fcW; dst = oFc + t * 8; }
    int lane = t & 63, kf = (t >> 6) & 3, nt = t >> 8;
    const float* s = src + (nt * 16 + (lane & 15)) * 128 + kf * 32 + 8 * (lane >> 4);
#pragma unroll
    for (int j = 0; j < 8; j++) dst[j] = f2bf(s[j]);
}

// K2: xi = x@W_ih^T (+bih, +bhh for r/z cols) in C-frag order. R17 version
// (8 frames/block, PLAIN loads -- R18's nontemporal x loads bypassed the
// replay-warm L3 and cost +28 us / +42 MB FETCH).
__global__ __launch_bounds__(512)
void xi_gemm(const float* __restrict__ x, const float* __restrict__ bih,
             const float* __restrict__ bhh, const short* __restrict__ wIh,
             short* __restrict__ xi_l) {
    __shared__ short xs[128 * 136];
    const int tid = threadIdx.x, wv = tid >> 6, ln = tid & 63;
    const int q = ln & 15, lg = ln >> 4;
    const int bg = blockIdx.x;
    const int sl0 = blockIdx.y * 8;
    {
        const int row = tid >> 2, kq = tid & 3;
        const int b = row & 15, dt = row >> 4;
        const float* xp = x + (((size_t)(bg * 16 + b)) * Tt + (sl0 + dt)) * Hd + kq * 32;
        short* dp = &xs[row * 136 + kq * 32];
#pragma unroll
        for (int h = 0; h < 2; h++) {
            f32x4 u0 = *(const f32x4*)&xp[16 * h];
            f32x4 u1 = *(const f32x4*)&xp[16 * h + 4];
            f32x4 u2 = *(const f32x4*)&xp[16 * h + 8];
            f32x4 u3 = *(const f32x4*)&xp[16 * h + 12];
            short8 s0, s1;
#pragma unroll
            for (int i = 0; i < 4; i++) { s0[i] = f2bf(u0[i]); s0[i+4] = f2bf(u1[i]);
                                          s1[i] = f2bf(u2[i]); s1[i+4] = f2bf(u3[i]); }
            *(short8*)(dp + 16 * h) = s0;
            *(short8*)(dp + 16 * h + 8) = s1;
        }
    }
    __syncthreads();
    short8 wb[3][4];
#pragma unroll
    for (int i = 0; i < 3; i++)
#pragma unroll
        for (int kf = 0; kf < 4; kf++)
            wb[i][kf] = *(const short8*)&wIh[(((wv + 8 * i) * 4 + kf) * 64 + ln) * 8];
    float biasv[3];
#pragma unroll
    for (int i = 0; i < 3; i++) {
        int c = (wv + 8 * i) * 16 + q;
        biasv[i] = bih[c] + (c < 256 ? bhh[c] : 0.f);
    }
#pragma unroll 2
    for (int mt = 0; mt < 8; mt++) {
        short8 af[4];
#pragma unroll
        for (int kf = 0; kf < 4; kf++)
            af[kf] = *(const short8*)&xs[(mt * 16 + q) * 136 + kf * 32 + 8 * lg];
        f32x4 c0 = {0,0,0,0}, c1 = {0,0,0,0}, c2 = {0,0,0,0};
#pragma unroll
        for (int kf = 0; kf < 4; kf++) {
            c0 = __builtin_amdgcn_mfma_f32_16x16x32_bf16(af[kf], wb[0][kf], c0, 0, 0, 0);
            c1 = __builtin_amdgcn_mfma_f32_16x16x32_bf16(af[kf], wb[1][kf], c1, 0, 0, 0);
            c2 = __builtin_amdgcn_mfma_f32_16x16x32_bf16(af[kf], wb[2][kf], c2, 0, 0, 0);
        }
#pragma unroll
        for (int i = 0; i < 3; i++) {
            f32x4 cc = (i == 0) ? c0 : (i == 1) ? c1 : c2;
            unsigned d0 = (unsigned)(unsigned short)f2bf(cc[0] + biasv[i]) |
                          ((unsigned)(unsigned short)f2bf(cc[1] + biasv[i]) << 16);
            unsigned d1 = (unsigned)(unsigned short)f2bf(cc[2] + biasv[i]) |
                          ((unsigned)(unsigned short)f2bf(cc[3] + biasv[i]) << 16);
            uint2 dd = {d0, d1};
            ((uint2*)xi_l)[(((size_t)bg * Tt + (sl0 + mt)) * 24 + (wv + 8 * i)) * 64 + ln] = dd;
        }
    }
}

// K3: R12 gru_chunk (best measured 92.8 us) + cvt_pk h-writeback (passed in
// R14/R18 variants; -12 VALU inst/thread-step). PLAIN out stores (R18's NT
// stores did not help; reverted with the NT loads).
__global__ __launch_bounds__(256)
void gru_chunk(const short* __restrict__ xi_l, const int* __restrict__ done,
               const float* __restrict__ h0,
               const float* __restrict__ bhh, const float* __restrict__ fcb,
               const short* __restrict__ wHh, const short* __restrict__ wFc,
               float* __restrict__ out, float* __restrict__ hlast) {
    __shared__ short hT[2][16 * 136];
    __shared__ int doneL[Tt * 16];
    __shared__ int rbL[16];
    const int tid = threadIdx.x, j = tid >> 6, ln = tid & 63;
    const int q = ln & 15, lg = ln >> 4;
    const int bg = blockIdx.x, ck = blockIdx.y;
    const int t_c = ck * CL, t_end = t_c + CL;

    {   // stage done[b][0..t_end) -> doneL[t][b]
        const int b = tid >> 4, i = tid & 15;
        const int* dp = done + (size_t)(bg * 16 + b) * Tt;
        for (int t = i; t < t_end; t += 16) doneL[t * 16 + b] = dp[t];
    }
    __syncthreads();
    if (tid < 16) {   // last reset before t_c
        int r = 0;
        for (int t = t_c - 1; t >= 0; --t)
            if (doneL[t * 16 + tid]) { r = t + 1; break; }
        rbL[tid] = r;
    }
    __syncthreads();
    int rmin = rbL[0];
#pragma unroll
    for (int b = 1; b < 16; b++) rmin = min(rmin, rbL[b]);

    short8 whh[6][4], wfc[2][4];
#pragma unroll
    for (int i = 0; i < 6; i++)
#pragma unroll
        for (int kf = 0; kf < 4; kf++)
            whh[i][kf] = *(const short8*)&wHh[(((j + 4 * i) * 4 + kf) * 64 + ln) * 8];
#pragma unroll
    for (int cs = 0; cs < 2; cs++)
#pragma unroll
        for (int kf = 0; kf < 4; kf++)
            wfc[cs][kf] = *(const short8*)&wFc[(((j + 4 * cs) * 4 + kf) * 64 + ln) * 8];
    float cbn[2], cbf[2];
#pragma unroll
    for (int cs = 0; cs < 2; cs++) {
        int c = 16 * j + 64 * cs + q;
        cbn[cs] = bhh[256 + c];
        cbf[cs] = fcb[c];
    }

    float h_reg[2][4];
#pragma unroll
    for (int cs = 0; cs < 2; cs++)
#pragma unroll
        for (int r = 0; r < 4; r++) {
            int bb = 4 * lg + r, c = 16 * j + 64 * cs + q;
            h_reg[cs][r] = (rbL[bb] == 0) ? h0[(size_t)(bg * 16 + bb) * Hd + c] : 0.f;
        }
    {   // hT[rmin&1] <- h_init (h0 if r_b==0 else 0)
        int row = tid >> 4, c0 = (tid & 15) * 8;
        short8 s0 = {0,0,0,0,0,0,0,0};
        if (rbL[row] == 0) {
            const float* hp = &h0[(size_t)(bg * 16 + row) * Hd + c0];
            f32x4 u0 = *(const f32x4*)&hp[0], u1 = *(const f32x4*)&hp[4];
#pragma unroll
            for (int i = 0; i < 4; i++) { s0[i] = f2bf(u0[i]); s0[i+4] = f2bf(u1[i]); }
        }
        *(short8*)&hT[rmin & 1][row * 136 + c0] = s0;
    }
    __syncthreads();

    // xi pointer: tile (j+4i) at xp + i*256 (uint2), one t = +1536
    const uint2* xp = (const uint2*)xi_l + ((size_t)bg * Tt + rmin) * 1536 + j * 64 + ln;
    uint2 cur[6];
#pragma unroll
    for (int i = 0; i < 6; i++) cur[i] = xp[i * 256];
    xp += 1536;

#pragma unroll 1
    for (int t = rmin; t < t_end; ++t) {
        const short* hTp = &hT[t & 1][0];
        short* hTn = &hT[(t + 1) & 1][0];
        short8 haf[4];
#pragma unroll
        for (int kf = 0; kf < 4; kf++)
            haf[kf] = *(const short8*)&hTp[q * 136 + kf * 32 + 8 * lg];

        // consume cur(t) -> acc init + xn8, then ISSUE loads for t+1 (older
        // than this iter's stores in vmcnt order)
        f32x4 acc[6];
#pragma unroll
        for (int i = 0; i < 4; i++) {
            f32x4 a = {bflo(cur[i].x), bfhi(cur[i].x), bflo(cur[i].y), bfhi(cur[i].y)};
            acc[i] = a;
        }
        { f32x4 a = {cbn[0], cbn[0], cbn[0], cbn[0]}; acc[4] = a; }
        { f32x4 a = {cbn[1], cbn[1], cbn[1], cbn[1]}; acc[5] = a; }
        uint2 xn8[2] = {cur[4], cur[5]};
        if (t + 1 < t_end) {
#pragma unroll
            for (int i = 0; i < 6; i++) cur[i] = xp[i * 256];
        }
        xp += 1536;

        if (t > t_c) {   // FC+ELU+stores for frame t-1 (un-reset haf)
            f32x4 fca[2];
            { f32x4 a = {cbf[0], cbf[0], cbf[0], cbf[0]}; fca[0] = a; }
            { f32x4 a = {cbf[1], cbf[1], cbf[1], cbf[1]}; fca[1] = a; }
#pragma unroll
            for (int kf = 0; kf < 4; kf++)
#pragma unroll
                for (int cs = 0; cs < 2; cs++)
                    fca[cs] = __builtin_amdgcn_mfma_f32_16x16x32_bf16(haf[kf], wfc[cs][kf], fca[cs], 0, 0, 0);
#pragma unroll
            for (int cs = 0; cs < 2; cs++)
#pragma unroll
                for (int r = 0; r < 4; r++) {
                    int bb = 4 * lg + r, c = 16 * j + 64 * cs + q;
                    float v = fca[cs][r];
                    float e = __expf(v) - 1.f;
                    v = v > 0.f ? v : e;
                    out[(((size_t)(bg * 16 + bb)) * Tt + (t - 1)) * Hd + c] = v;
                }
        }

        if (t > 0) {   // reset haf in place (FC above used un-reset value)
            int dn = doneL[(t - 1) * 16 + q];
            short8 z8 = {0,0,0,0,0,0,0,0};
#pragma unroll
            for (int kf = 0; kf < 4; kf++) haf[kf] = dn ? z8 : haf[kf];
        }
        __builtin_amdgcn_s_setprio(1);   // favor the h-critical region
#pragma unroll
        for (int kf = 0; kf < 4; kf++)
#pragma unroll
            for (int i = 0; i < 6; i++)
                acc[i] = __builtin_amdgcn_mfma_f32_16x16x32_bf16(haf[kf], whh[i][kf], acc[i], 0, 0, 0);

        float rstf[4] = {1.f, 1.f, 1.f, 1.f};
        if (t > 0) {
            int4 dd = *(const int4*)&doneL[(t - 1) * 16 + 4 * lg];
            rstf[0] = dd.x ? 0.f : 1.f; rstf[1] = dd.y ? 0.f : 1.f;
            rstf[2] = dd.z ? 0.f : 1.f; rstf[3] = dd.w ? 0.f : 1.f;
        }
#pragma unroll
        for (int cs = 0; cs < 2; cs++) {
            float hn_[4];
#pragma unroll
            for (int r = 0; r < 4; r++) {
                float rg = __builtin_amdgcn_rcpf(1.f + __expf(-acc[cs][r]));
                float zg = __builtin_amdgcn_rcpf(1.f + __expf(-acc[2 + cs][r]));
                float xn = (r == 0) ? bflo(xn8[cs].x) : (r == 1) ? bfhi(xn8[cs].x)
                         : (r == 2) ? bflo(xn8[cs].y) : bfhi(xn8[cs].y);
                float aa = fmaf(rg, acc[4 + cs][r], xn);
                float ng = 1.f - 2.f * __builtin_amdgcn_rcpf(__expf(2.f * aa) + 1.f);
                float hp = h_reg[cs][r] * rstf[r];
                float hn = (1.f - zg) * ng + zg * hp;
                h_reg[cs][r] = hn;                       // un-reset
                hn_[r] = hn;
            }
            unsigned pk0, pk1;
            asm("v_cvt_pk_bf16_f32 %0, %1, %2" : "=v"(pk0) : "v"(hn_[0]), "v"(hn_[1]));
            asm("v_cvt_pk_bf16_f32 %0, %1, %2" : "=v"(pk1) : "v"(hn_[2]), "v"(hn_[3]));
            hTn[(4 * lg + 0) * 136 + 16 * j + 64 * cs + q] = (short)pk0;
            hTn[(4 * lg + 1) * 136 + 16 * j + 64 * cs + q] = (short)(pk0 >> 16);
            hTn[(4 * lg + 2) * 136 + 16 * j + 64 * cs + q] = (short)pk1;
            hTn[(4 * lg + 3) * 136 + 16 * j + 64 * cs + q] = (short)(pk1 >> 16);
        }
        __builtin_amdgcn_s_setprio(0);
        // raw barrier: lgkmcnt(0) only, semantic intrinsic
        __builtin_amdgcn_sched_barrier(0);
        __builtin_amdgcn_s_waitcnt(0xC07F);
        __builtin_amdgcn_s_barrier();
        __builtin_amdgcn_sched_barrier(0);
    }
    {   // epilogue FC for frame t_end-1 (slot t_end&1 holds h_{t_end-1})
        const short* hTp = &hT[t_end & 1][0];
        short8 haf[4];
#pragma unroll
        for (int kf = 0; kf < 4; kf++)
            haf[kf] = *(const short8*)&hTp[q * 136 + kf * 32 + 8 * lg];
        f32x4 fca[2];
        { f32x4 a = {cbf[0], cbf[0], cbf[0], cbf[0]}; fca[0] = a; }
        { f32x4 a = {cbf[1], cbf[1], cbf[1], cbf[1]}; fca[1] = a; }
#pragma unroll
        for (int kf = 0; kf < 4; kf++)
#pragma unroll
            for (int cs = 0; cs < 2; cs++)
                fca[cs] = __builtin_amdgcn_mfma_f32_16x16x32_bf16(haf[kf], wfc[cs][kf], fca[cs], 0, 0, 0);
#pragma unroll
        for (int cs = 0; cs < 2; cs++)
#pragma unroll
            for (int r = 0; r < 4; r++) {
                int bb = 4 * lg + r, c = 16 * j + 64 * cs + q;
                float v = fca[cs][r];
                float e = __expf(v) - 1.f;
                v = v > 0.f ? v : e;
                out[(((size_t)(bg * 16 + bb)) * Tt + (t_end - 1)) * Hd + c] = v;
            }
    }
    if (ck == NCK - 1) {   // h after step 255, un-reset
#pragma unroll
        for (int cs = 0; cs < 2; cs++)
#pragma unroll
            for (int r = 0; r < 4; r++) {
                int bb = 4 * lg + r, c = 16 * j + 64 * cs + q;
                hlast[(size_t)(bg * 16 + bb) * Hd + c] = h_reg[cs][r];
            }
    }
}

extern "C" void kernel_launch(void* const* d_in, const int* in_sizes, int n_in,
                              void* d_out, int out_size, void* d_ws, size_t ws_size,
                              hipStream_t stream) {
    const float* x   = (const float*)d_in[0];
    const float* h0  = (const float*)d_in[1];
    const int*   dn  = (const int*)d_in[2];
    const float* Wih = (const float*)d_in[3];
    const float* Whh = (const float*)d_in[4];
    const float* bih = (const float*)d_in[5];
    const float* bhh = (const float*)d_in[6];
    const float* fcW = (const float*)d_in[7];
    const float* fcb = (const float*)d_in[8];

    short* wIh = (short*)d_ws;                 // 96 KB
    short* wHh = wIh + 49152;                  // 96 KB
    short* wFc = wHh + 49152;                  // 32 KB
    short* xi_l = wFc + 16384;                 // full-T xi: 201 MB
    float* out = (float*)d_out;
    float* hlast = out + (size_t)Bb * Tt * Hd;

    prep_weights<<<56, 256, 0, stream>>>(Wih, Whh, fcW, wIh, wHh, wFc);
    xi_gemm<<<dim3(64, Tt / 8), 512, 0, stream>>>(x, bih, bhh, wIh, xi_l);
    gru_chunk<<<dim3(64, NCK), 256, 0, stream>>>(xi_l, dn, h0, bhh, fcb,
                                                 wHh, wFc, out, hlast);
}